// Round 1
// baseline (7301.698 us; speedup 1.0000x reference)
//
#include <hip/hip_runtime.h>
#include <math.h>

#define THREADS 256

// No LDS, no barriers. All weight fetches are wave-uniform -> scalar pipe
// (s_load_dwordx4 through K$), VALU does only FMAs + tanh/exp.
__global__ __launch_bounds__(THREADS, 2)
void fused_net(const float* __restrict__ x,
               const float* __restrict__ W1, const float* __restrict__ b1,
               const float* __restrict__ W4, const float* __restrict__ b4,
               const float* __restrict__ W2, const float* __restrict__ b2,
               const float* __restrict__ gum,
               float* __restrict__ out)
{
    const int tid = threadIdx.x;
    const int row = blockIdx.x * THREADS + tid;   // grid sized exactly
    const float* xr   = x   + (size_t)row * 64;
    const float* grow = gum + (size_t)row * 320;
    float*       orow = out + (size_t)row * 384;

    // ================= Phase A: h1 = tanh(x @ W1 + b1), rank-1 over k ======
    float acc[100];
    #pragma unroll
    for (int i = 0; i < 100; ++i) acc[i] = 0.f;

    float xk = xr[0];
    #pragma clang loop unroll(disable)
    for (int k = 0; k < 64; ++k) {
        float xn = xr[(k + 1) & 63];             // distance-1 prefetch, in-bounds
        const float4* wr = (const float4*)(W1 + k * 100);   // uniform -> s_load
        #pragma unroll
        for (int q = 0; q < 25; ++q) {
            float4 w = wr[q];
            acc[4*q+0] = fmaf(xk, w.x, acc[4*q+0]);
            acc[4*q+1] = fmaf(xk, w.y, acc[4*q+1]);
            acc[4*q+2] = fmaf(xk, w.z, acc[4*q+2]);
            acc[4*q+3] = fmaf(xk, w.w, acc[4*q+3]);
        }
        xk = xn;
    }
    #pragma unroll
    for (int i = 0; i < 100; ++i) acc[i] = tanhf(acc[i] + b1[i]);
    // acc[] = h1, literal-indexed registers

    // ===== Phase B: h2 col-groups of 4 (W4 natural layout, uniform loads) ==
    // park h2 in this row's out slice (overwritten by Phase D later)
    #pragma clang loop unroll(disable)
    for (int c = 0; c < 100; c += 4) {
        float s0 = 0.f, s1 = 0.f, s2 = 0.f, s3 = 0.f;
        #pragma unroll
        for (int i = 0; i < 100; ++i) {
            float4 w = *(const float4*)(W4 + i * 100 + c);  // uniform -> s_load
            float h = acc[i];
            s0 = fmaf(h, w.x, s0);
            s1 = fmaf(h, w.y, s1);
            s2 = fmaf(h, w.z, s2);
            s3 = fmaf(h, w.w, s3);
        }
        float4 hv;
        hv.x = tanhf(s0 + b4[c+0]);
        hv.y = tanhf(s1 + b4[c+1]);
        hv.z = tanhf(s2 + b4[c+2]);
        hv.w = tanhf(s3 + b4[c+3]);
        *(float4*)(orow + 64 + c) = hv;          // park (16B-aligned)
    }

    // same-thread RAW readback into literal-indexed registers
    float h2r[100];
    #pragma unroll
    for (int q = 0; q < 25; ++q) {
        float4 v = *(const float4*)(orow + 64 + 4*q);
        h2r[4*q+0] = v.x; h2r[4*q+1] = v.y; h2r[4*q+2] = v.z; h2r[4*q+3] = v.w;
    }

    // ================= Phase C: y1 softmax, online pass + recompute pass ===
    float m = -1e30f, ssum = 0.f;
    #pragma clang loop unroll(disable)
    for (int c = 0; c < 64; c += 4) {
        float s0 = 0.f, s1 = 0.f, s2 = 0.f, s3 = 0.f;
        #pragma unroll
        for (int i = 0; i < 100; ++i) {
            float4 w = *(const float4*)(W2 + i * 384 + c);  // uniform -> s_load
            float h = h2r[i];
            s0 = fmaf(h, w.x, s0);
            s1 = fmaf(h, w.y, s1);
            s2 = fmaf(h, w.z, s2);
            s3 = fmaf(h, w.w, s3);
        }
        float z0 = s0 + b2[c+0], z1 = s1 + b2[c+1];
        float z2 = s2 + b2[c+2], z3 = s3 + b2[c+3];
        float mg = fmaxf(fmaxf(z0, z1), fmaxf(z2, z3));
        float mn = fmaxf(m, mg);
        ssum = ssum * expf(m - mn)
             + expf(z0 - mn) + expf(z1 - mn) + expf(z2 - mn) + expf(z3 - mn);
        m = mn;
    }
    const float rinv = 1.f / ssum;
    #pragma clang loop unroll(disable)
    for (int c = 0; c < 64; c += 4) {
        float s0 = 0.f, s1 = 0.f, s2 = 0.f, s3 = 0.f;
        #pragma unroll
        for (int i = 0; i < 100; ++i) {
            float4 w = *(const float4*)(W2 + i * 384 + c);  // K$-hot by now
            float h = h2r[i];
            s0 = fmaf(h, w.x, s0);
            s1 = fmaf(h, w.y, s1);
            s2 = fmaf(h, w.z, s2);
            s3 = fmaf(h, w.w, s3);
        }
        float z0 = s0 + b2[c+0], z1 = s1 + b2[c+1];
        float z2 = s2 + b2[c+2], z3 = s3 + b2[c+3];
        float4 y;
        y.x = expf(z0 - m) * rinv;
        y.y = expf(z1 - m) * rinv;
        y.z = expf(z2 - m) * rinv;
        y.w = expf(z3 - m) * rinv;
        *(float4*)(orow + c) = y;                // y1 written exactly once
    }

    // ============ Phase D: straight-through one-hot, 4 groups/chunk ========
    #pragma clang loop unroll(disable)
    for (int t = 0; t < 16; ++t) {
        const int c0 = 64 + 20 * t;

        // gumbel for this chunk: issued up front, consumed after the ~2500-op
        // dot -> latency fully hidden, no double-buffer registers needed
        float gcur[20];
        {
            const float* gp = grow + 20 * t;
            #pragma unroll
            for (int u = 0; u < 5; ++u) {
                float4 g4 = *(const float4*)(gp + 4*u);
                gcur[4*u+0] = g4.x; gcur[4*u+1] = g4.y;
                gcur[4*u+2] = g4.z; gcur[4*u+3] = g4.w;
            }
        }

        float a[20];
        #pragma unroll
        for (int j = 0; j < 20; ++j) a[j] = 0.f;

        #pragma unroll
        for (int i = 0; i < 100; ++i) {
            const float h = h2r[i];
            const float* wp = W2 + i * 384 + c0;            // uniform -> s_load
            #pragma unroll
            for (int u = 0; u < 5; ++u) {
                float4 w = *(const float4*)(wp + 4*u);
                a[4*u+0] = fmaf(h, w.x, a[4*u+0]);
                a[4*u+1] = fmaf(h, w.y, a[4*u+1]);
                a[4*u+2] = fmaf(h, w.z, a[4*u+2]);
                a[4*u+3] = fmaf(h, w.w, a[4*u+3]);
            }
        }

        float ob[20];
        #pragma unroll
        for (int g = 0; g < 4; ++g) {
            float z[5];
            #pragma unroll
            for (int j = 0; j < 5; ++j)
                z[j] = a[5*g+j] + b2[c0 + 5*g + j] + gcur[5*g+j];
            int best = 0; float bz = z[0];
            #pragma unroll
            for (int j = 1; j < 5; ++j) { if (z[j] > bz) { bz = z[j]; best = j; } }
            #pragma unroll
            for (int j = 0; j < 5; ++j) ob[5*g+j] = (j == best) ? 1.f : 0.f;
        }
        #pragma unroll
        for (int u = 0; u < 5; ++u) {
            float4 o4;
            o4.x = ob[4*u+0]; o4.y = ob[4*u+1];
            o4.z = ob[4*u+2]; o4.w = ob[4*u+3];
            *(float4*)(orow + c0 + 4*u) = o4;    // 16B-aligned one-hot store
        }
    }
}

extern "C" void kernel_launch(void* const* d_in, const int* in_sizes, int n_in,
                              void* d_out, int out_size, void* d_ws, size_t ws_size,
                              hipStream_t stream) {
    const float* x  = (const float*)d_in[0];
    const float* W1 = (const float*)d_in[1];
    const float* b1 = (const float*)d_in[2];
    const float* W4 = (const float*)d_in[3];
    const float* b4 = (const float*)d_in[4];
    const float* W2 = (const float*)d_in[5];
    const float* b2 = (const float*)d_in[6];
    const float* g  = (const float*)d_in[7];
    float* out = (float*)d_out;

    const int B = in_sizes[0] / 64;              // 262144
    const int grid = B / THREADS;                // exact: 1024 blocks
    hipLaunchKernelGGL(fused_net, dim3(grid), dim3(THREADS), 0, stream,
                       x, W1, b1, W4, b4, W2, b2, g, out);
}